// Round 6
// baseline (103.289 us; speedup 1.0000x reference)
//
#include <hip/hip_runtime.h>
#include <math.h>

#define NG 16
#define GW 128
#define NEGV -1.0e9f
#define EPSBN 1e-5f
#define MIN_SCORE 0.1f
#define TOLK 1e-7f
#define NBIN 1024
#define NPBMAX 256
#define EPT 16           // edges per thread in scatter
#define KCAP 256         // global kept-node cap
#define ECAP 2048        // surviving-edge cap
#define ROWCAP 16        // per-graph LDS fast-path row cap
#define LECAP 256        // per-graph LDS fast-path edge cap

// ---------- helpers ----------
__device__ __forceinline__ unsigned encf(float f) {
  unsigned u = __float_as_uint(f);
  return (u & 0x80000000u) ? ~u : (u | 0x80000000u);
}
__device__ __forceinline__ float decf(unsigned u) {
  unsigned b = (u & 0x80000000u) ? (u & 0x7fffffffu) : ~u;
  return __uint_as_float(b);
}
__device__ __forceinline__ float eluf(float v) { return v > 0.0f ? v : expm1f(v); }

// stage a 128x128 f32 matrix into LDS with coalesced float4 loads
__device__ __forceinline__ void stage_w(const float* __restrict__ w, float* wbuf, int t) {
  const float4* w4 = (const float4*)w;
  float4* b4 = (float4*)wbuf;
  #pragma unroll
  for (int i = 0; i < 16; ++i) b4[t + 256 * i] = w4[t + 256 * i];
}

// ---------- kernels ----------
__global__ void k_zero(int* __restrict__ bincnt, int* __restrict__ counters,
                       unsigned* __restrict__ smax_e, float* __restrict__ sumex) {
  int t = threadIdx.x;
  for (int i = t; i < NBIN; i += blockDim.x) bincnt[i] = 0;
  if (t < NG) { smax_e[t] = encf(-INFINITY); sumex[t] = 0.0f; }
  if (t == 0) { counters[0] = 0; counters[1] = 0; }
}

// direct bucketed scatter (per-bin capacity regions) + xw init
__global__ __launch_bounds__(1024) void k_scatter(
    const int* __restrict__ src, const int* __restrict__ dst, int ne, int shift,
    int cap, int* __restrict__ bincnt, unsigned* __restrict__ sorted,
    const float* __restrict__ x, const float* __restrict__ gcn_w,
    float* __restrict__ xw, int n) {
  __shared__ int lh[NBIN];
  __shared__ int gb[NBIN];
  int t = threadIdx.x;
  long gid = (long)blockIdx.x * 1024 + t;
  long gs = (long)gridDim.x * 1024;
  float w0 = gcn_w[0], w1 = gcn_w[1];
  for (long i = gid; i < n; i += gs) xw[i] = x[2 * i] * w0 + x[2 * i + 1] * w1;
  for (int b = t; b < NBIN; b += 1024) lh[b] = 0;
  __syncthreads();
  long ebase = (long)blockIdx.x * (1024 * EPT);
  int rank[EPT], dv[EPT];
  #pragma unroll
  for (int k = 0; k < EPT; ++k) {
    long e = ebase + (long)k * 1024 + t;
    rank[k] = 0; dv[k] = 0;
    if (e < ne) { dv[k] = dst[e]; rank[k] = atomicAdd(&lh[dv[k] >> shift], 1); }
  }
  __syncthreads();
  for (int b = t; b < NBIN; b += 1024)
    gb[b] = lh[b] ? atomicAdd(&bincnt[b], lh[b]) : 0;
  __syncthreads();
  #pragma unroll
  for (int k = 0; k < EPT; ++k) {
    long e = ebase + (long)k * 1024 + t;
    if (e < ne) {
      int d = dv[k], bin = d >> shift;
      int pos = gb[bin] + rank[k];
      if (pos < cap)
        sorted[(size_t)bin * cap + pos] =
            ((unsigned)(d & ((1 << shift) - 1)) << 24) | (unsigned)src[e];
    }
  }
}

// per-bucket: deg count (LDS) -> dinv + y = xw*dinv
__global__ void k_c1(const unsigned* __restrict__ sorted, const int* __restrict__ bincnt,
                     int cap, const float* __restrict__ xw, float* __restrict__ dinv,
                     float* __restrict__ y, int n, int shift) {
  __shared__ int ldeg[NPBMAX];
  int b = blockIdx.x;
  int off = b << shift;
  if (off >= n) return;
  int npb = 1 << shift;
  int t = threadIdx.x;
  for (int j = t; j < npb; j += blockDim.x) ldeg[j] = 0;
  __syncthreads();
  size_t s0 = (size_t)b * cap;
  int cnt = bincnt[b]; if (cnt > cap) cnt = cap;
  for (int i = t; i < cnt; i += blockDim.x)
    atomicAdd(&ldeg[sorted[s0 + i] >> 24], 1);
  __syncthreads();
  for (int j = t; j < npb; j += blockDim.x) {
    int g = off + j;
    if (g < n) {
      float dv = rsqrtf((float)(ldeg[j] + 1));   // +1 self loop
      dinv[g] = dv;
      y[g] = xw[g] * dv;
    }
  }
}

// per-bucket: agg -> s_raw; per-graph max AND unnormalized sum(exp(s))
__global__ void k_c2(const unsigned* __restrict__ sorted, const int* __restrict__ bincnt,
                     int cap, const float* __restrict__ y, const float* __restrict__ xw,
                     const float* __restrict__ dinv, const int* __restrict__ batch,
                     const float* __restrict__ gcn_b, const float* __restrict__ topk_w,
                     float* __restrict__ s_raw, unsigned* __restrict__ smax_e,
                     float* __restrict__ sumex, int n, int shift) {
  __shared__ float lt[NPBMAX];
  __shared__ unsigned ls[NG];
  __shared__ float lsum[NG];
  int b = blockIdx.x;
  int off = b << shift;
  if (off >= n) return;
  int npb = 1 << shift;
  int t = threadIdx.x;
  for (int j = t; j < npb; j += blockDim.x) lt[j] = 0.0f;
  if (t < NG) { ls[t] = encf(-INFINITY); lsum[t] = 0.0f; }
  __syncthreads();
  size_t s0 = (size_t)b * cap;
  int cnt = bincnt[b]; if (cnt > cap) cnt = cap;
  for (int i = t; i < cnt; i += blockDim.x) {
    unsigned p = sorted[s0 + i];
    atomicAdd(&lt[p >> 24], y[p & 0xFFFFFFu]);
  }
  __syncthreads();
  float gb_ = gcn_b[0], tw = topk_w[0];
  for (int j = t; j < npb; j += blockDim.x) {
    int g = off + j;
    if (g < n) {
      float dv = dinv[g];
      float attn = dv * lt[j] + xw[g] * dv * dv + gb_;
      float s = attn * tw;
      s_raw[g] = s;
      int bb = batch[g];
      atomicMax(&ls[bb], encf(s));
      atomicAdd(&lsum[bb], expf(s));
    }
  }
  __syncthreads();
  if (t < NG) {
    if (ls[t] != encf(-INFINITY)) atomicMax(&smax_e[t], ls[t]);
    if (lsum[t] != 0.0f) atomicAdd(&sumex[t], lsum[t]);
  }
}

__global__ void k_compact_n(const float* __restrict__ s_raw, const float* __restrict__ sumex,
                            const unsigned* __restrict__ smax_e,
                            const int* __restrict__ batch, const float* __restrict__ x,
                            int* __restrict__ kmap, int* __restrict__ kbatch,
                            float* __restrict__ hk, float* __restrict__ degfc,
                            int* __restrict__ counters, int n) {
  int i = blockIdx.x * blockDim.x + threadIdx.x;
  if (i >= n) return;
  if (i < KCAP) degfc[i] = 0.0f;                  // idempotent pre-zero for compact_e
  int b = batch[i];
  float se = sumex[b];
  float score = expf(s_raw[i]) / se;
  float ms = expf(decf(smax_e[b])) / se;          // == max score (monotone fp)
  float thr = fminf(ms - TOLK, MIN_SCORE);
  int m = -1;
  if (score > thr) {
    int idx = atomicAdd(&counters[0], 1);
    if (idx < KCAP) {
      m = idx;
      kbatch[idx] = b;
      hk[2 * idx]     = x[2 * i] * score;
      hk[2 * idx + 1] = x[2 * i + 1] * score;
    }
  }
  kmap[i] = m;
}

// per-bucket surviving-edge compaction
__global__ void k_compact_e(const unsigned* __restrict__ sorted, const int* __restrict__ bincnt,
                            int cap, const int* __restrict__ kmap,
                            int* __restrict__ eks, int* __restrict__ ekd,
                            float* __restrict__ degfc, int* __restrict__ counters,
                            int n, int shift) {
  int b = blockIdx.x;
  int off = b << shift;
  if (off >= n) return;
  size_t s0 = (size_t)b * cap;
  int cnt = bincnt[b]; if (cnt > cap) cnt = cap;
  for (int i = threadIdx.x; i < cnt; i += blockDim.x) {
    unsigned p = sorted[s0 + i];
    int ks = kmap[p & 0xFFFFFFu];
    if (ks < 0) continue;
    int kd = kmap[off + (int)(p >> 24)];
    if (kd < 0) continue;
    int j = atomicAdd(&counters[1], 1);
    if (j < ECAP) {
      eks[j] = ks;
      ekd[j] = kd;
      atomicAdd(&degfc[kd], 1.0f);
    }
  }
}

// slow-path cheb layer (global buffers, direct weight loads) — rarely/never taken
__device__ void tail_layer_slow(const float* hin, float* tx, float* hout,
                                const float* __restrict__ w0, const float* __restrict__ w1,
                                const float* __restrict__ cb,
                                const float* __restrict__ bng, const float* __restrict__ bnb,
                                const float* __restrict__ bnm, const float* __restrict__ bnv,
                                int L, int R, int S,
                                const int* kl, const int* rows_g,
                                const int* __restrict__ kbatch,
                                const int* __restrict__ eks, const int* __restrict__ ekd,
                                const float* __restrict__ degfc,
                                unsigned* lgm, int g, int t) {
  for (int i = t; i < R * GW; i += 256) tx[i] = 0.0f;
  __syncthreads();
  for (int e = t; e < S; e += 256) {
    int kd = ekd[e];
    int dr = kl[kd];
    if (dr < 0) continue;
    int sr = kl[eks[e]];
    if (sr < 0) continue;
    float dfs = degfc[eks[e]], dfd = degfc[kd];
    float nf = (dfs > 0.f ? rsqrtf(dfs) : 0.f) * (dfd > 0.f ? rsqrtf(dfd) : 0.f);
    for (int c = 0; c < GW; ++c)
      atomicAdd(&tx[dr * GW + c], -hin[sr * GW + c] * nf);
  }
  __syncthreads();
  int j = t & 127, ih = t >> 7;
  float sc = bng[L * GW + j] * rsqrtf(bnv[L * GW + j] + EPSBN);
  float mn = bnm[L * GW + j], bt = bnb[L * GW + j], bj = cb[j];
  for (int i = ih; i < R; i += 2) {
    float acc = bj;
    for (int k = 0; k < GW; ++k)
      acc += hin[i * GW + k] * w0[k * GW + j] + tx[i * GW + k] * w1[k * GW + j];
    float v = eluf(acc);
    v = (v - mn) * sc + bt;
    if (hout) hout[i * GW + j] = v;
    if (kbatch[rows_g[i]] == g) atomicMax(&lgm[L * GW + j], encf(v));
  }
  __syncthreads();
}

// fast-path cheb layer: weights staged in LDS, static-unrolled row accs
template <int MR>
__device__ void layer_fast(const float* hin, const float* txl, float* hout,
                           const float* __restrict__ w0g, const float* __restrict__ w1g,
                           const float* __restrict__ cb,
                           const float* __restrict__ bng, const float* __restrict__ bnb,
                           const float* __restrict__ bnm, const float* __restrict__ bnv,
                           int L, int R, const int* rows_g,
                           const int* __restrict__ kbatch,
                           unsigned* lgm, float* wbuf, int g, int t) {
  int j = t & 127, ih = t >> 7;
  float bj = cb[j];
  float acc[MR];
  #pragma unroll
  for (int r = 0; r < MR; ++r) acc[r] = bj;
  stage_w(w0g, wbuf, t);
  __syncthreads();
  for (int k = 0; k < GW; ++k) {
    float wv = wbuf[k * GW + j];
    #pragma unroll
    for (int r = 0; r < MR; ++r) {
      int row = ih + 2 * r;
      if (row < R) acc[r] += hin[row * GW + k] * wv;
    }
  }
  __syncthreads();
  stage_w(w1g, wbuf, t);
  __syncthreads();
  for (int k = 0; k < GW; ++k) {
    float wv = wbuf[k * GW + j];
    #pragma unroll
    for (int r = 0; r < MR; ++r) {
      int row = ih + 2 * r;
      if (row < R) acc[r] += txl[row * GW + k] * wv;
    }
  }
  float sc = bng[L * GW + j] * rsqrtf(bnv[L * GW + j] + EPSBN);
  float mn = bnm[L * GW + j], bt = bnb[L * GW + j];
  #pragma unroll
  for (int r = 0; r < MR; ++r) {
    int row = ih + 2 * r;
    if (row < R) {
      float v = eluf(acc[r]);
      v = (v - mn) * sc + bt;
      if (hout) hout[row * GW + j] = v;
      if (kbatch[rows_g[row]] == g) atomicMax(&lgm[L * GW + j], encf(v));
    }
  }
  __syncthreads();
}

// 16 blocks, one per graph: halo rows, 3x(agg+cheb+bn) with LDS-staged weights,
// gmax in LDS, staged MLP, log_softmax
__global__ __launch_bounds__(256) void k_tail(
    const float* __restrict__ hk, const int* __restrict__ kbatch,
    const int* __restrict__ counters,
    const int* __restrict__ eks, const int* __restrict__ ekd,
    const float* __restrict__ degfc,
    const float* __restrict__ c0w0, const float* __restrict__ c0w1, const float* __restrict__ c0b,
    const float* __restrict__ c1w0, const float* __restrict__ c1w1, const float* __restrict__ c1b,
    const float* __restrict__ c2w0, const float* __restrict__ c2w1, const float* __restrict__ c2b,
    const float* __restrict__ bng, const float* __restrict__ bnb,
    const float* __restrict__ bnm, const float* __restrict__ bnv,
    const float* __restrict__ l0w, const float* __restrict__ l0b,
    const float* __restrict__ l1w, const float* __restrict__ l1b,
    const float* __restrict__ lfw, const float* __restrict__ lfb,
    float* __restrict__ g_hA, float* __restrict__ g_hB, float* __restrict__ g_tx,
    float* __restrict__ g_t0, float* __restrict__ out) {
  __shared__ float wbuf[GW * GW];                       // 64 KB weight stage
  __shared__ float sA[ROWCAP * GW], sB[ROWCAP * GW], sT[ROWCAP * GW];
  __shared__ float t0v[ROWCAP * 2];
  __shared__ int kl[KCAP];
  __shared__ int rows_g[KCAP];
  __shared__ int les[LECAP], led[LECAP];
  __shared__ float lenf[LECAP];
  __shared__ unsigned lgm[3 * GW];
  __shared__ int cnts[2];
  __shared__ float red[256];
  __shared__ float mlp0[32], mlp1[8], lg3[3];

  int g = blockIdx.x, t = threadIdx.x;
  int K = counters[0]; if (K > KCAP) K = KCAP;
  int S = counters[1]; if (S > ECAP) S = ECAP;
  if (t == 0) { cnts[0] = 0; cnts[1] = 0; }
  for (int i = t; i < KCAP; i += 256) kl[i] = -1;
  for (int i = t; i < 3 * GW; i += 256) lgm[i] = encf(NEGV);
  __syncthreads();
  for (int i = t; i < K; i += 256)
    if (kbatch[i] == g) { int r = atomicAdd(&cnts[0], 1); rows_g[r] = i; }
  __syncthreads();
  int R0 = cnts[0];
  for (int r = t; r < R0; r += 256) kl[rows_g[r]] = r;
  __syncthreads();
  // 2-hop halo expansion (serial, S is tiny)
  if (t == 0) {
    for (int pass = 0; pass < 2; ++pass) {
      int Rcur = cnts[0];
      for (int e = 0; e < S; ++e) {
        int kd = ekd[e];
        if (kl[kd] >= 0 && kl[kd] < Rcur) {
          int ks = eks[e];
          if (kl[ks] < 0) { int r = cnts[0]++; rows_g[r] = ks; kl[ks] = r; }
        }
      }
    }
  }
  __syncthreads();
  int R = cnts[0];
  // local edge list (edges into any local row)
  for (int e = t; e < S; e += 256) {
    int kd = ekd[e];
    if (kl[kd] >= 0) {
      int j = atomicAdd(&cnts[1], 1);
      if (j < LECAP) {
        les[j] = eks[e];
        led[j] = kl[kd];
        float dfs = degfc[eks[e]], dfd = degfc[kd];
        lenf[j] = (dfs > 0.f ? rsqrtf(dfs) : 0.f) * (dfd > 0.f ? rsqrtf(dfd) : 0.f);
      }
    }
  }
  __syncthreads();
  int LE = cnts[1]; if (LE > LECAP) LE = LECAP;
  bool fast = (R <= ROWCAP) && (cnts[1] <= LECAP);

  if (fast) {
    // --- layer 0 (D=2), weights tiny: direct ---
    for (int i = t; i < R * 2; i += 256) t0v[i] = 0.0f;
    __syncthreads();
    for (int idx = t; idx < LE * 2; idx += 256) {
      int e = idx >> 1, c = idx & 1;
      atomicAdd(&t0v[led[e] * 2 + c], -hk[les[e] * 2 + c] * lenf[e]);
    }
    __syncthreads();
    {
      int j = t & 127, ih = t >> 7;
      float sc = bng[j] * rsqrtf(bnv[j] + EPSBN);
      float mn = bnm[j], bt = bnb[j];
      for (int i = ih; i < R; i += 2) {
        int gi = rows_g[i];
        float acc = c0b[j] + hk[gi * 2] * c0w0[j] + hk[gi * 2 + 1] * c0w0[GW + j]
                  + t0v[i * 2] * c0w1[j] + t0v[i * 2 + 1] * c0w1[GW + j];
        float v = eluf(acc);
        v = (v - mn) * sc + bt;
        sA[i * GW + j] = v;
        if (kbatch[gi] == g) atomicMax(&lgm[j], encf(v));
      }
    }
    __syncthreads();
    // --- layer 1: agg(sA)->sT, MM staged -> sB ---
    for (int i = t; i < R * GW; i += 256) sT[i] = 0.0f;
    __syncthreads();
    for (int idx = t; idx < LE * GW; idx += 256) {
      int e = idx >> 7, c = idx & 127;
      int sr = kl[les[e]];
      if (sr >= 0) atomicAdd(&sT[led[e] * GW + c], -sA[sr * GW + c] * lenf[e]);
    }
    __syncthreads();
    if (R <= 2)
      layer_fast<1>(sA, sT, sB, c1w0, c1w1, c1b, bng, bnb, bnm, bnv, 1, R,
                    rows_g, kbatch, lgm, wbuf, g, t);
    else
      layer_fast<8>(sA, sT, sB, c1w0, c1w1, c1b, bng, bnb, bnm, bnv, 1, R,
                    rows_g, kbatch, lgm, wbuf, g, t);
    // --- layer 2: agg(sB)->sT, MM staged (no store) ---
    for (int i = t; i < R * GW; i += 256) sT[i] = 0.0f;
    __syncthreads();
    for (int idx = t; idx < LE * GW; idx += 256) {
      int e = idx >> 7, c = idx & 127;
      int sr = kl[les[e]];
      if (sr >= 0) atomicAdd(&sT[led[e] * GW + c], -sB[sr * GW + c] * lenf[e]);
    }
    __syncthreads();
    if (R <= 2)
      layer_fast<1>(sB, sT, nullptr, c2w0, c2w1, c2b, bng, bnb, bnm, bnv, 2, R,
                    rows_g, kbatch, lgm, wbuf, g, t);
    else
      layer_fast<8>(sB, sT, nullptr, c2w0, c2w1, c2b, bng, bnb, bnm, bnv, 2, R,
                    rows_g, kbatch, lgm, wbuf, g, t);
  } else {
    // --- slow path: global buffers, unstaged (R > ROWCAP; effectively unreachable) ---
    float* hA  = g_hA + (size_t)g * KCAP * GW;
    float* hB  = g_hB + (size_t)g * KCAP * GW;
    float* tx  = g_tx + (size_t)g * KCAP * GW;
    float* t0p = g_t0 + (size_t)g * KCAP * 2;
    for (int i = t; i < R * 2; i += 256) t0p[i] = 0.0f;
    __syncthreads();
    for (int e = t; e < S; e += 256) {
      int kd = ekd[e];
      int dr = kl[kd];
      if (dr < 0) continue;
      int ks = eks[e];
      float dfs = degfc[ks], dfd = degfc[kd];
      float nf = (dfs > 0.f ? rsqrtf(dfs) : 0.f) * (dfd > 0.f ? rsqrtf(dfd) : 0.f);
      atomicAdd(&t0p[dr * 2],     -hk[ks * 2] * nf);
      atomicAdd(&t0p[dr * 2 + 1], -hk[ks * 2 + 1] * nf);
    }
    __syncthreads();
    {
      int j = t & 127, ih = t >> 7;
      float sc = bng[j] * rsqrtf(bnv[j] + EPSBN);
      float mn = bnm[j], bt = bnb[j];
      for (int i = ih; i < R; i += 2) {
        int gi = rows_g[i];
        float acc = c0b[j] + hk[gi * 2] * c0w0[j] + hk[gi * 2 + 1] * c0w0[GW + j]
                  + t0p[i * 2] * c0w1[j] + t0p[i * 2 + 1] * c0w1[GW + j];
        float v = eluf(acc);
        v = (v - mn) * sc + bt;
        hA[i * GW + j] = v;
        if (kbatch[gi] == g) atomicMax(&lgm[j], encf(v));
      }
    }
    __syncthreads();
    tail_layer_slow(hA, tx, hB, c1w0, c1w1, c1b, bng, bnb, bnm, bnv, 1, R, S,
                    kl, rows_g, kbatch, eks, ekd, degfc, lgm, g, t);
    tail_layer_slow(hB, tx, nullptr, c2w0, c2w1, c2b, bng, bnb, bnm, bnv, 2, R, S,
                    kl, rows_g, kbatch, eks, ekd, degfc, lgm, g, t);
  }

  // --- MLP: stage l0w(12288)+l1w(256)+lfw(24) into wbuf ---
  {
    const float4* a4 = (const float4*)l0w;
    float4* b4 = (float4*)wbuf;
    #pragma unroll
    for (int i = 0; i < 12; ++i) b4[t + 256 * i] = a4[t + 256 * i];
    wbuf[12288 + t] = l1w[t & 255];
    if (t < 24) wbuf[12544 + t] = lfw[t];
  }
  __syncthreads();
  // lin0: 32 outputs x 8 k-chunks of 48
  {
    int jo = t & 31, kb = t >> 5;
    float a = 0.f;
    for (int kk = 0; kk < 48; ++kk) {
      int k = kb * 48 + kk;
      a += decf(lgm[k]) * wbuf[k * 32 + jo];
    }
    red[t] = a;
  }
  __syncthreads();
  if (t < 32) {
    float acc = l0b[t];
    for (int b2 = 0; b2 < 8; ++b2) acc += red[b2 * 32 + t];
    mlp0[t] = eluf(acc);
  }
  __syncthreads();
  if (t < 8) {
    float acc = l1b[t];
    for (int k = 0; k < 32; ++k) acc += mlp0[k] * wbuf[12288 + k * 8 + t];
    mlp1[t] = eluf(acc);
  }
  __syncthreads();
  if (t < 3) {
    float acc = lfb[t];
    for (int k = 0; k < 8; ++k) acc += mlp1[k] * wbuf[12544 + k * 3 + t];
    lg3[t] = acc;
  }
  __syncthreads();
  if (t == 0) {
    float a = lg3[0], b = lg3[1], c = lg3[2];
    float m = fmaxf(a, fmaxf(b, c));
    float ls = m + logf(expf(a - m) + expf(b - m) + expf(c - m));
    out[g * 3 + 0] = a - ls;
    out[g * 3 + 1] = b - ls;
    out[g * 3 + 2] = c - ls;
  }
}

// ---------- launcher ----------
extern "C" void kernel_launch(void* const* d_in, const int* in_sizes, int n_in,
                              void* d_out, int out_size, void* d_ws, size_t ws_size,
                              hipStream_t stream) {
  const float* x      = (const float*)d_in[0];
  const int*   ei     = (const int*)d_in[1];
  const int*   batch  = (const int*)d_in[2];
  const float* gcn_w  = (const float*)d_in[3];
  const float* gcn_b  = (const float*)d_in[4];
  const float* topk_w = (const float*)d_in[5];
  const float* c0w0 = (const float*)d_in[6],  *c0w1 = (const float*)d_in[7],  *c0b = (const float*)d_in[8];
  const float* c1w0 = (const float*)d_in[9],  *c1w1 = (const float*)d_in[10], *c1b = (const float*)d_in[11];
  const float* c2w0 = (const float*)d_in[12], *c2w1 = (const float*)d_in[13], *c2b = (const float*)d_in[14];
  const float* bng = (const float*)d_in[15], *bnb = (const float*)d_in[16];
  const float* bnm = (const float*)d_in[17], *bnv = (const float*)d_in[18];
  const float* l0w = (const float*)d_in[19], *l0b = (const float*)d_in[20];
  const float* l1w = (const float*)d_in[21], *l1b = (const float*)d_in[22];
  const float* lfw = (const float*)d_in[23], *lfb = (const float*)d_in[24];
  float* out = (float*)d_out;

  const int n  = in_sizes[2];       // N nodes
  const int ne = in_sizes[1] / 2;   // E edges
  const int* src = ei;
  const int* dst = ei + ne;

  int shift = 0;
  while (((n - 1) >> shift) >= NBIN) shift++;
  if (shift > 8) shift = 8;  // supports n <= 262144
  const int nbins = ((n - 1) >> shift) + 1;
  int avg = (ne + nbins - 1) / nbins;
  int cap = avg + (int)(8.0 * sqrt((double)avg)) + 64;
  cap = (cap + 15) & ~15;

  char* bp = (char*)d_ws;
  size_t off = 0;
  auto A = [&](size_t bytes) -> void* {
    void* r = (void*)(bp + off);
    off += (bytes + 255) & ~(size_t)255;
    return r;
  };
  float*    xw     = (float*)A((size_t)n * 4);
  float*    dinv   = (float*)A((size_t)n * 4);
  float*    y      = (float*)A((size_t)n * 4);
  float*    s_raw  = (float*)A((size_t)n * 4);
  int*      kmap   = (int*)A((size_t)n * 4);
  unsigned* sorted = (unsigned*)A((size_t)NBIN * cap * 4);
  int*      bincnt = (int*)A(NBIN * 4);
  unsigned* smax_e = (unsigned*)A(NG * 4);
  float*    sumex  = (float*)A(NG * 4);
  int*      counters = (int*)A(8);
  int*      kbatch = (int*)A((size_t)KCAP * 4);
  float*    degfc  = (float*)A((size_t)KCAP * 4);
  float*    hk     = (float*)A((size_t)KCAP * 8);
  int*      eks    = (int*)A((size_t)ECAP * 4);
  int*      ekd    = (int*)A((size_t)ECAP * 4);
  float*    g_hA   = (float*)A((size_t)NG * KCAP * GW * 4);
  float*    g_hB   = (float*)A((size_t)NG * KCAP * GW * 4);
  float*    g_tx   = (float*)A((size_t)NG * KCAP * GW * 4);
  float*    g_t0   = (float*)A((size_t)NG * KCAP * 8);

  const int nbN = (n + 255) / 256;
  const int nbS = (ne + 1024 * EPT - 1) / (1024 * EPT);

  k_zero<<<1, 1024, 0, stream>>>(bincnt, counters, smax_e, sumex);
  k_scatter<<<nbS, 1024, 0, stream>>>(src, dst, ne, shift, cap, bincnt, sorted,
                                      x, gcn_w, xw, n);
  k_c1<<<NBIN, 256, 0, stream>>>(sorted, bincnt, cap, xw, dinv, y, n, shift);
  k_c2<<<NBIN, 256, 0, stream>>>(sorted, bincnt, cap, y, xw, dinv, batch, gcn_b,
                                 topk_w, s_raw, smax_e, sumex, n, shift);
  k_compact_n<<<nbN, 256, 0, stream>>>(s_raw, sumex, smax_e, batch, x, kmap,
                                       kbatch, hk, degfc, counters, n);
  k_compact_e<<<NBIN, 256, 0, stream>>>(sorted, bincnt, cap, kmap, eks, ekd,
                                        degfc, counters, n, shift);
  k_tail<<<NG, 256, 0, stream>>>(hk, kbatch, counters, eks, ekd, degfc,
                                 c0w0, c0w1, c0b, c1w0, c1w1, c1b, c2w0, c2w1, c2b,
                                 bng, bnb, bnm, bnv, l0w, l0b, l1w, l1b, lfw, lfb,
                                 g_hA, g_hB, g_tx, g_t0, out);
}

// Round 7
// 100.885 us; speedup vs baseline: 1.0238x; 1.0238x over previous
//
#include <hip/hip_runtime.h>
#include <math.h>

#define NG 16
#define GW 128
#define NEGV -1.0e9f
#define EPSBN 1e-5f
#define MIN_SCORE 0.1f
#define TOLK 1e-7f
#define NBIN 1024
#define NPBMAX 256
#define EPT 4            // edges per thread in scatter (4 -> 392 blocks: full CU coverage)
#define KCAP 256         // global kept-node cap
#define ECAP 2048        // surviving-edge cap
#define ROWCAP 16        // per-graph LDS fast-path row cap
#define LECAP 256        // per-graph LDS fast-path edge cap

// ---------- helpers ----------
__device__ __forceinline__ unsigned encf(float f) {
  unsigned u = __float_as_uint(f);
  return (u & 0x80000000u) ? ~u : (u | 0x80000000u);
}
__device__ __forceinline__ float decf(unsigned u) {
  unsigned b = (u & 0x80000000u) ? (u & 0x7fffffffu) : ~u;
  return __uint_as_float(b);
}
__device__ __forceinline__ float eluf(float v) { return v > 0.0f ? v : expm1f(v); }

// stage a 128x128 f32 matrix into LDS with coalesced float4 loads
__device__ __forceinline__ void stage_w(const float* __restrict__ w, float* wbuf, int t) {
  const float4* w4 = (const float4*)w;
  float4* b4 = (float4*)wbuf;
  #pragma unroll
  for (int i = 0; i < 16; ++i) b4[t + 256 * i] = w4[t + 256 * i];
}

// ---------- kernels ----------
__global__ void k_zero(int* __restrict__ bincnt, int* __restrict__ counters,
                       unsigned* __restrict__ smax_e, float* __restrict__ sumex) {
  int t = threadIdx.x;
  for (int i = t; i < NBIN; i += blockDim.x) bincnt[i] = 0;
  if (t < NG) { smax_e[t] = encf(-INFINITY); sumex[t] = 0.0f; }
  if (t == 0) { counters[0] = 0; counters[1] = 0; }
}

// direct bucketed scatter (per-bin capacity regions) + xw init
__global__ __launch_bounds__(1024) void k_scatter(
    const int* __restrict__ src, const int* __restrict__ dst, int ne, int shift,
    int cap, int* __restrict__ bincnt, unsigned* __restrict__ sorted,
    const float* __restrict__ x, const float* __restrict__ gcn_w,
    float* __restrict__ xw, int n) {
  __shared__ int lh[NBIN];
  __shared__ int gb[NBIN];
  int t = threadIdx.x;
  long gid = (long)blockIdx.x * 1024 + t;
  long gs = (long)gridDim.x * 1024;
  float w0 = gcn_w[0], w1 = gcn_w[1];
  for (long i = gid; i < n; i += gs) xw[i] = x[2 * i] * w0 + x[2 * i + 1] * w1;
  for (int b = t; b < NBIN; b += 1024) lh[b] = 0;
  __syncthreads();
  long ebase = (long)blockIdx.x * (1024 * EPT);
  int rank[EPT], dv[EPT];
  #pragma unroll
  for (int k = 0; k < EPT; ++k) {
    long e = ebase + (long)k * 1024 + t;
    rank[k] = 0; dv[k] = 0;
    if (e < ne) { dv[k] = dst[e]; rank[k] = atomicAdd(&lh[dv[k] >> shift], 1); }
  }
  __syncthreads();
  for (int b = t; b < NBIN; b += 1024)
    gb[b] = lh[b] ? atomicAdd(&bincnt[b], lh[b]) : 0;
  __syncthreads();
  #pragma unroll
  for (int k = 0; k < EPT; ++k) {
    long e = ebase + (long)k * 1024 + t;
    if (e < ne) {
      int d = dv[k], bin = d >> shift;
      int pos = gb[bin] + rank[k];
      if (pos < cap)
        sorted[(size_t)bin * cap + pos] =
            ((unsigned)(d & ((1 << shift) - 1)) << 24) | (unsigned)src[e];
    }
  }
}

// per-bucket: deg count (LDS) -> dinv + y = xw*dinv   (uint4-vectorized reads)
__global__ void k_c1(const unsigned* __restrict__ sorted, const int* __restrict__ bincnt,
                     int cap, const float* __restrict__ xw, float* __restrict__ dinv,
                     float* __restrict__ y, int n, int shift) {
  __shared__ int ldeg[NPBMAX];
  int b = blockIdx.x;
  int off = b << shift;
  if (off >= n) return;
  int npb = 1 << shift;
  int t = threadIdx.x;
  for (int j = t; j < npb; j += blockDim.x) ldeg[j] = 0;
  __syncthreads();
  const uint4* s4 = (const uint4*)(sorted + (size_t)b * cap);
  int cnt = bincnt[b]; if (cnt > cap) cnt = cap;
  int nv = cnt >> 2;
  for (int i = t; i < nv; i += blockDim.x) {
    uint4 p = s4[i];
    atomicAdd(&ldeg[p.x >> 24], 1);
    atomicAdd(&ldeg[p.y >> 24], 1);
    atomicAdd(&ldeg[p.z >> 24], 1);
    atomicAdd(&ldeg[p.w >> 24], 1);
  }
  const unsigned* ss = sorted + (size_t)b * cap;
  for (int i = (nv << 2) + t; i < cnt; i += blockDim.x)
    atomicAdd(&ldeg[ss[i] >> 24], 1);
  __syncthreads();
  for (int j = t; j < npb; j += blockDim.x) {
    int g = off + j;
    if (g < n) {
      float dv = rsqrtf((float)(ldeg[j] + 1));   // +1 self loop
      dinv[g] = dv;
      y[g] = xw[g] * dv;
    }
  }
}

// per-bucket: agg -> s_raw; per-graph max AND unnormalized sum(exp(s))
__global__ void k_c2(const unsigned* __restrict__ sorted, const int* __restrict__ bincnt,
                     int cap, const float* __restrict__ y, const float* __restrict__ xw,
                     const float* __restrict__ dinv, const int* __restrict__ batch,
                     const float* __restrict__ gcn_b, const float* __restrict__ topk_w,
                     float* __restrict__ s_raw, unsigned* __restrict__ smax_e,
                     float* __restrict__ sumex, int n, int shift) {
  __shared__ float lt[NPBMAX];
  __shared__ unsigned ls[NG];
  __shared__ float lsum[NG];
  int b = blockIdx.x;
  int off = b << shift;
  if (off >= n) return;
  int npb = 1 << shift;
  int t = threadIdx.x;
  for (int j = t; j < npb; j += blockDim.x) lt[j] = 0.0f;
  if (t < NG) { ls[t] = encf(-INFINITY); lsum[t] = 0.0f; }
  __syncthreads();
  const uint4* s4 = (const uint4*)(sorted + (size_t)b * cap);
  int cnt = bincnt[b]; if (cnt > cap) cnt = cap;
  int nv = cnt >> 2;
  for (int i = t; i < nv; i += blockDim.x) {
    uint4 p = s4[i];
    float ya = y[p.x & 0xFFFFFFu];
    float yb = y[p.y & 0xFFFFFFu];
    float yc = y[p.z & 0xFFFFFFu];
    float yd = y[p.w & 0xFFFFFFu];
    atomicAdd(&lt[p.x >> 24], ya);
    atomicAdd(&lt[p.y >> 24], yb);
    atomicAdd(&lt[p.z >> 24], yc);
    atomicAdd(&lt[p.w >> 24], yd);
  }
  const unsigned* ss = sorted + (size_t)b * cap;
  for (int i = (nv << 2) + t; i < cnt; i += blockDim.x) {
    unsigned p = ss[i];
    atomicAdd(&lt[p >> 24], y[p & 0xFFFFFFu]);
  }
  __syncthreads();
  float gb_ = gcn_b[0], tw = topk_w[0];
  for (int j = t; j < npb; j += blockDim.x) {
    int g = off + j;
    if (g < n) {
      float dv = dinv[g];
      float attn = dv * lt[j] + xw[g] * dv * dv + gb_;
      float s = attn * tw;
      s_raw[g] = s;
      int bb = batch[g];
      atomicMax(&ls[bb], encf(s));
      atomicAdd(&lsum[bb], expf(s));
    }
  }
  __syncthreads();
  if (t < NG) {
    if (ls[t] != encf(-INFINITY)) atomicMax(&smax_e[t], ls[t]);
    if (lsum[t] != 0.0f) atomicAdd(&sumex[t], lsum[t]);
  }
}

__global__ void k_compact_n(const float* __restrict__ s_raw, const float* __restrict__ sumex,
                            const unsigned* __restrict__ smax_e,
                            const int* __restrict__ batch, const float* __restrict__ x,
                            int* __restrict__ kmap, int* __restrict__ kbatch,
                            float* __restrict__ hk, float* __restrict__ degfc,
                            int* __restrict__ counters, int n) {
  int i = blockIdx.x * blockDim.x + threadIdx.x;
  if (i >= n) return;
  if (i < KCAP) degfc[i] = 0.0f;                  // idempotent pre-zero for compact_e
  int b = batch[i];
  float se = sumex[b];
  float score = expf(s_raw[i]) / se;
  float ms = expf(decf(smax_e[b])) / se;          // == max score (monotone fp)
  float thr = fminf(ms - TOLK, MIN_SCORE);
  int m = -1;
  if (score > thr) {
    int idx = atomicAdd(&counters[0], 1);
    if (idx < KCAP) {
      m = idx;
      kbatch[idx] = b;
      hk[2 * idx]     = x[2 * i] * score;
      hk[2 * idx + 1] = x[2 * i + 1] * score;
    }
  }
  kmap[i] = m;
}

// per-bucket surviving-edge compaction (uint4-vectorized)
__global__ void k_compact_e(const unsigned* __restrict__ sorted, const int* __restrict__ bincnt,
                            int cap, const int* __restrict__ kmap,
                            int* __restrict__ eks, int* __restrict__ ekd,
                            float* __restrict__ degfc, int* __restrict__ counters,
                            int n, int shift) {
  int b = blockIdx.x;
  int off = b << shift;
  if (off >= n) return;
  const uint4* s4 = (const uint4*)(sorted + (size_t)b * cap);
  int cnt = bincnt[b]; if (cnt > cap) cnt = cap;
  int nv = cnt >> 2;
  auto proc = [&](unsigned p) {
    int ks = kmap[p & 0xFFFFFFu];
    if (ks < 0) return;
    int kd = kmap[off + (int)(p >> 24)];
    if (kd < 0) return;
    int j = atomicAdd(&counters[1], 1);
    if (j < ECAP) {
      eks[j] = ks;
      ekd[j] = kd;
      atomicAdd(&degfc[kd], 1.0f);
    }
  };
  for (int i = threadIdx.x; i < nv; i += blockDim.x) {
    uint4 p = s4[i];
    proc(p.x); proc(p.y); proc(p.z); proc(p.w);
  }
  const unsigned* ss = sorted + (size_t)b * cap;
  for (int i = (nv << 2) + threadIdx.x; i < cnt; i += blockDim.x) proc(ss[i]);
}

// slow-path cheb layer (global buffers, direct weight loads) — effectively unreachable
__device__ void tail_layer_slow(const float* hin, float* tx, float* hout,
                                const float* __restrict__ w0, const float* __restrict__ w1,
                                const float* __restrict__ cb,
                                const float* __restrict__ bng, const float* __restrict__ bnb,
                                const float* __restrict__ bnm, const float* __restrict__ bnv,
                                int L, int R, int S,
                                const int* kl, const int* rows_g,
                                const int* __restrict__ kbatch,
                                const int* __restrict__ eks, const int* __restrict__ ekd,
                                const float* __restrict__ degfc,
                                unsigned* lgm, int g, int t) {
  for (int i = t; i < R * GW; i += 256) tx[i] = 0.0f;
  __syncthreads();
  for (int e = t; e < S; e += 256) {
    int kd = ekd[e];
    int dr = kl[kd];
    if (dr < 0) continue;
    int sr = kl[eks[e]];
    if (sr < 0) continue;
    float dfs = degfc[eks[e]], dfd = degfc[kd];
    float nf = (dfs > 0.f ? rsqrtf(dfs) : 0.f) * (dfd > 0.f ? rsqrtf(dfd) : 0.f);
    for (int c = 0; c < GW; ++c)
      atomicAdd(&tx[dr * GW + c], -hin[sr * GW + c] * nf);
  }
  __syncthreads();
  int j = t & 127, ih = t >> 7;
  float sc = bng[L * GW + j] * rsqrtf(bnv[L * GW + j] + EPSBN);
  float mn = bnm[L * GW + j], bt = bnb[L * GW + j], bj = cb[j];
  for (int i = ih; i < R; i += 2) {
    float acc = bj;
    for (int k = 0; k < GW; ++k)
      acc += hin[i * GW + k] * w0[k * GW + j] + tx[i * GW + k] * w1[k * GW + j];
    float v = eluf(acc);
    v = (v - mn) * sc + bt;
    if (hout) hout[i * GW + j] = v;
    if (kbatch[rows_g[i]] == g) atomicMax(&lgm[L * GW + j], encf(v));
  }
  __syncthreads();
}

// fast-path cheb layer: weights staged in LDS, static-unrolled row accs
template <int MR>
__device__ void layer_fast(const float* hin, const float* txl, float* hout,
                           const float* __restrict__ w0g, const float* __restrict__ w1g,
                           const float* __restrict__ cb,
                           const float* __restrict__ bng, const float* __restrict__ bnb,
                           const float* __restrict__ bnm, const float* __restrict__ bnv,
                           int L, int R, const int* rows_g,
                           const int* __restrict__ kbatch,
                           unsigned* lgm, float* wbuf, int g, int t) {
  int j = t & 127, ih = t >> 7;
  float bj = cb[j];
  float acc[MR];
  #pragma unroll
  for (int r = 0; r < MR; ++r) acc[r] = bj;
  stage_w(w0g, wbuf, t);
  __syncthreads();
  for (int k = 0; k < GW; ++k) {
    float wv = wbuf[k * GW + j];
    #pragma unroll
    for (int r = 0; r < MR; ++r) {
      int row = ih + 2 * r;
      if (row < R) acc[r] += hin[row * GW + k] * wv;
    }
  }
  __syncthreads();
  stage_w(w1g, wbuf, t);
  __syncthreads();
  for (int k = 0; k < GW; ++k) {
    float wv = wbuf[k * GW + j];
    #pragma unroll
    for (int r = 0; r < MR; ++r) {
      int row = ih + 2 * r;
      if (row < R) acc[r] += txl[row * GW + k] * wv;
    }
  }
  float sc = bng[L * GW + j] * rsqrtf(bnv[L * GW + j] + EPSBN);
  float mn = bnm[L * GW + j], bt = bnb[L * GW + j];
  #pragma unroll
  for (int r = 0; r < MR; ++r) {
    int row = ih + 2 * r;
    if (row < R) {
      float v = eluf(acc[r]);
      v = (v - mn) * sc + bt;
      if (hout) hout[row * GW + j] = v;
      if (kbatch[rows_g[row]] == g) atomicMax(&lgm[L * GW + j], encf(v));
    }
  }
  __syncthreads();
}

// 16 blocks, one per graph: halo rows, 3x(agg+cheb+bn) with LDS-staged weights,
// gmax in LDS, staged MLP, log_softmax
__global__ __launch_bounds__(256) void k_tail(
    const float* __restrict__ hk, const int* __restrict__ kbatch,
    const int* __restrict__ counters,
    const int* __restrict__ eks, const int* __restrict__ ekd,
    const float* __restrict__ degfc,
    const float* __restrict__ c0w0, const float* __restrict__ c0w1, const float* __restrict__ c0b,
    const float* __restrict__ c1w0, const float* __restrict__ c1w1, const float* __restrict__ c1b,
    const float* __restrict__ c2w0, const float* __restrict__ c2w1, const float* __restrict__ c2b,
    const float* __restrict__ bng, const float* __restrict__ bnb,
    const float* __restrict__ bnm, const float* __restrict__ bnv,
    const float* __restrict__ l0w, const float* __restrict__ l0b,
    const float* __restrict__ l1w, const float* __restrict__ l1b,
    const float* __restrict__ lfw, const float* __restrict__ lfb,
    float* __restrict__ g_hA, float* __restrict__ g_hB, float* __restrict__ g_tx,
    float* __restrict__ g_t0, float* __restrict__ out) {
  __shared__ float wbuf[GW * GW];                       // 64 KB weight stage
  __shared__ float sA[ROWCAP * GW], sB[ROWCAP * GW], sT[ROWCAP * GW];
  __shared__ float t0v[ROWCAP * 2];
  __shared__ int kl[KCAP];
  __shared__ int rows_g[KCAP];
  __shared__ int les[LECAP], led[LECAP];
  __shared__ float lenf[LECAP];
  __shared__ unsigned lgm[3 * GW];
  __shared__ int cnts[2];
  __shared__ float red[256];
  __shared__ float mlp0[32], mlp1[8], lg3[3];

  int g = blockIdx.x, t = threadIdx.x;
  int K = counters[0]; if (K > KCAP) K = KCAP;
  int S = counters[1]; if (S > ECAP) S = ECAP;
  if (t == 0) { cnts[0] = 0; cnts[1] = 0; }
  for (int i = t; i < KCAP; i += 256) kl[i] = -1;
  for (int i = t; i < 3 * GW; i += 256) lgm[i] = encf(NEGV);
  __syncthreads();
  for (int i = t; i < K; i += 256)
    if (kbatch[i] == g) { int r = atomicAdd(&cnts[0], 1); rows_g[r] = i; }
  __syncthreads();
  int R0 = cnts[0];
  for (int r = t; r < R0; r += 256) kl[rows_g[r]] = r;
  __syncthreads();
  // 2-hop halo expansion (serial, S is tiny)
  if (t == 0) {
    for (int pass = 0; pass < 2; ++pass) {
      int Rcur = cnts[0];
      for (int e = 0; e < S; ++e) {
        int kd = ekd[e];
        if (kl[kd] >= 0 && kl[kd] < Rcur) {
          int ks = eks[e];
          if (kl[ks] < 0) { int r = cnts[0]++; rows_g[r] = ks; kl[ks] = r; }
        }
      }
    }
  }
  __syncthreads();
  int R = cnts[0];
  // local edge list (edges into any local row)
  for (int e = t; e < S; e += 256) {
    int kd = ekd[e];
    if (kl[kd] >= 0) {
      int j = atomicAdd(&cnts[1], 1);
      if (j < LECAP) {
        les[j] = eks[e];
        led[j] = kl[kd];
        float dfs = degfc[eks[e]], dfd = degfc[kd];
        lenf[j] = (dfs > 0.f ? rsqrtf(dfs) : 0.f) * (dfd > 0.f ? rsqrtf(dfd) : 0.f);
      }
    }
  }
  __syncthreads();
  int LE = cnts[1]; if (LE > LECAP) LE = LECAP;
  bool fast = (R <= ROWCAP) && (cnts[1] <= LECAP);

  if (fast) {
    // --- layer 0 (D=2), weights tiny: direct ---
    for (int i = t; i < R * 2; i += 256) t0v[i] = 0.0f;
    __syncthreads();
    for (int idx = t; idx < LE * 2; idx += 256) {
      int e = idx >> 1, c = idx & 1;
      atomicAdd(&t0v[led[e] * 2 + c], -hk[les[e] * 2 + c] * lenf[e]);
    }
    __syncthreads();
    {
      int j = t & 127, ih = t >> 7;
      float sc = bng[j] * rsqrtf(bnv[j] + EPSBN);
      float mn = bnm[j], bt = bnb[j];
      for (int i = ih; i < R; i += 2) {
        int gi = rows_g[i];
        float acc = c0b[j] + hk[gi * 2] * c0w0[j] + hk[gi * 2 + 1] * c0w0[GW + j]
                  + t0v[i * 2] * c0w1[j] + t0v[i * 2 + 1] * c0w1[GW + j];
        float v = eluf(acc);
        v = (v - mn) * sc + bt;
        sA[i * GW + j] = v;
        if (kbatch[gi] == g) atomicMax(&lgm[j], encf(v));
      }
    }
    __syncthreads();
    // --- layer 1: agg(sA)->sT, MM staged -> sB ---
    for (int i = t; i < R * GW; i += 256) sT[i] = 0.0f;
    __syncthreads();
    for (int idx = t; idx < LE * GW; idx += 256) {
      int e = idx >> 7, c = idx & 127;
      int sr = kl[les[e]];
      if (sr >= 0) atomicAdd(&sT[led[e] * GW + c], -sA[sr * GW + c] * lenf[e]);
    }
    __syncthreads();
    if (R <= 2)
      layer_fast<1>(sA, sT, sB, c1w0, c1w1, c1b, bng, bnb, bnm, bnv, 1, R,
                    rows_g, kbatch, lgm, wbuf, g, t);
    else
      layer_fast<8>(sA, sT, sB, c1w0, c1w1, c1b, bng, bnb, bnm, bnv, 1, R,
                    rows_g, kbatch, lgm, wbuf, g, t);
    // --- layer 2: agg(sB)->sT, MM staged (no store) ---
    for (int i = t; i < R * GW; i += 256) sT[i] = 0.0f;
    __syncthreads();
    for (int idx = t; idx < LE * GW; idx += 256) {
      int e = idx >> 7, c = idx & 127;
      int sr = kl[les[e]];
      if (sr >= 0) atomicAdd(&sT[led[e] * GW + c], -sB[sr * GW + c] * lenf[e]);
    }
    __syncthreads();
    if (R <= 2)
      layer_fast<1>(sB, sT, nullptr, c2w0, c2w1, c2b, bng, bnb, bnm, bnv, 2, R,
                    rows_g, kbatch, lgm, wbuf, g, t);
    else
      layer_fast<8>(sB, sT, nullptr, c2w0, c2w1, c2b, bng, bnb, bnm, bnv, 2, R,
                    rows_g, kbatch, lgm, wbuf, g, t);
  } else {
    // --- slow path: global buffers (R > ROWCAP; effectively unreachable) ---
    float* hA  = g_hA + (size_t)g * KCAP * GW;
    float* hB  = g_hB + (size_t)g * KCAP * GW;
    float* tx  = g_tx + (size_t)g * KCAP * GW;
    float* t0p = g_t0 + (size_t)g * KCAP * 2;
    for (int i = t; i < R * 2; i += 256) t0p[i] = 0.0f;
    __syncthreads();
    for (int e = t; e < S; e += 256) {
      int kd = ekd[e];
      int dr = kl[kd];
      if (dr < 0) continue;
      int ks = eks[e];
      float dfs = degfc[ks], dfd = degfc[kd];
      float nf = (dfs > 0.f ? rsqrtf(dfs) : 0.f) * (dfd > 0.f ? rsqrtf(dfd) : 0.f);
      atomicAdd(&t0p[dr * 2],     -hk[ks * 2] * nf);
      atomicAdd(&t0p[dr * 2 + 1], -hk[ks * 2 + 1] * nf);
    }
    __syncthreads();
    {
      int j = t & 127, ih = t >> 7;
      float sc = bng[j] * rsqrtf(bnv[j] + EPSBN);
      float mn = bnm[j], bt = bnb[j];
      for (int i = ih; i < R; i += 2) {
        int gi = rows_g[i];
        float acc = c0b[j] + hk[gi * 2] * c0w0[j] + hk[gi * 2 + 1] * c0w0[GW + j]
                  + t0p[i * 2] * c0w1[j] + t0p[i * 2 + 1] * c0w1[GW + j];
        float v = eluf(acc);
        v = (v - mn) * sc + bt;
        hA[i * GW + j] = v;
        if (kbatch[gi] == g) atomicMax(&lgm[j], encf(v));
      }
    }
    __syncthreads();
    tail_layer_slow(hA, tx, hB, c1w0, c1w1, c1b, bng, bnb, bnm, bnv, 1, R, S,
                    kl, rows_g, kbatch, eks, ekd, degfc, lgm, g, t);
    tail_layer_slow(hB, tx, nullptr, c2w0, c2w1, c2b, bng, bnb, bnm, bnv, 2, R, S,
                    kl, rows_g, kbatch, eks, ekd, degfc, lgm, g, t);
  }

  // --- MLP: stage l0w(12288)+l1w(256)+lfw(24) into wbuf ---
  {
    const float4* a4 = (const float4*)l0w;
    float4* b4 = (float4*)wbuf;
    #pragma unroll
    for (int i = 0; i < 12; ++i) b4[t + 256 * i] = a4[t + 256 * i];
    wbuf[12288 + t] = l1w[t & 255];
    if (t < 24) wbuf[12544 + t] = lfw[t];
  }
  __syncthreads();
  // lin0: 32 outputs x 8 k-chunks of 48
  {
    int jo = t & 31, kb = t >> 5;
    float a = 0.f;
    for (int kk = 0; kk < 48; ++kk) {
      int k = kb * 48 + kk;
      a += decf(lgm[k]) * wbuf[k * 32 + jo];
    }
    red[t] = a;
  }
  __syncthreads();
  if (t < 32) {
    float acc = l0b[t];
    for (int b2 = 0; b2 < 8; ++b2) acc += red[b2 * 32 + t];
    mlp0[t] = eluf(acc);
  }
  __syncthreads();
  if (t < 8) {
    float acc = l1b[t];
    for (int k = 0; k < 32; ++k) acc += mlp0[k] * wbuf[12288 + k * 8 + t];
    mlp1[t] = eluf(acc);
  }
  __syncthreads();
  if (t < 3) {
    float acc = lfb[t];
    for (int k = 0; k < 8; ++k) acc += mlp1[k] * wbuf[12544 + k * 3 + t];
    lg3[t] = acc;
  }
  __syncthreads();
  if (t == 0) {
    float a = lg3[0], b = lg3[1], c = lg3[2];
    float m = fmaxf(a, fmaxf(b, c));
    float ls = m + logf(expf(a - m) + expf(b - m) + expf(c - m));
    out[g * 3 + 0] = a - ls;
    out[g * 3 + 1] = b - ls;
    out[g * 3 + 2] = c - ls;
  }
}

// ---------- launcher ----------
extern "C" void kernel_launch(void* const* d_in, const int* in_sizes, int n_in,
                              void* d_out, int out_size, void* d_ws, size_t ws_size,
                              hipStream_t stream) {
  const float* x      = (const float*)d_in[0];
  const int*   ei     = (const int*)d_in[1];
  const int*   batch  = (const int*)d_in[2];
  const float* gcn_w  = (const float*)d_in[3];
  const float* gcn_b  = (const float*)d_in[4];
  const float* topk_w = (const float*)d_in[5];
  const float* c0w0 = (const float*)d_in[6],  *c0w1 = (const float*)d_in[7],  *c0b = (const float*)d_in[8];
  const float* c1w0 = (const float*)d_in[9],  *c1w1 = (const float*)d_in[10], *c1b = (const float*)d_in[11];
  const float* c2w0 = (const float*)d_in[12], *c2w1 = (const float*)d_in[13], *c2b = (const float*)d_in[14];
  const float* bng = (const float*)d_in[15], *bnb = (const float*)d_in[16];
  const float* bnm = (const float*)d_in[17], *bnv = (const float*)d_in[18];
  const float* l0w = (const float*)d_in[19], *l0b = (const float*)d_in[20];
  const float* l1w = (const float*)d_in[21], *l1b = (const float*)d_in[22];
  const float* lfw = (const float*)d_in[23], *lfb = (const float*)d_in[24];
  float* out = (float*)d_out;

  const int n  = in_sizes[2];       // N nodes
  const int ne = in_sizes[1] / 2;   // E edges
  const int* src = ei;
  const int* dst = ei + ne;

  int shift = 0;
  while (((n - 1) >> shift) >= NBIN) shift++;
  if (shift > 8) shift = 8;  // supports n <= 262144
  const int nbins = ((n - 1) >> shift) + 1;
  int avg = (ne + nbins - 1) / nbins;
  int cap = avg + (int)(8.0 * sqrt((double)avg)) + 64;
  cap = (cap + 15) & ~15;

  char* bp = (char*)d_ws;
  size_t off = 0;
  auto A = [&](size_t bytes) -> void* {
    void* r = (void*)(bp + off);
    off += (bytes + 255) & ~(size_t)255;
    return r;
  };
  float*    xw     = (float*)A((size_t)n * 4);
  float*    dinv   = (float*)A((size_t)n * 4);
  float*    y      = (float*)A((size_t)n * 4);
  float*    s_raw  = (float*)A((size_t)n * 4);
  int*      kmap   = (int*)A((size_t)n * 4);
  unsigned* sorted = (unsigned*)A((size_t)NBIN * cap * 4);
  int*      bincnt = (int*)A(NBIN * 4);
  unsigned* smax_e = (unsigned*)A(NG * 4);
  float*    sumex  = (float*)A(NG * 4);
  int*      counters = (int*)A(8);
  int*      kbatch = (int*)A((size_t)KCAP * 4);
  float*    degfc  = (float*)A((size_t)KCAP * 4);
  float*    hk     = (float*)A((size_t)KCAP * 8);
  int*      eks    = (int*)A((size_t)ECAP * 4);
  int*      ekd    = (int*)A((size_t)ECAP * 4);
  float*    g_hA   = (float*)A((size_t)NG * KCAP * GW * 4);
  float*    g_hB   = (float*)A((size_t)NG * KCAP * GW * 4);
  float*    g_tx   = (float*)A((size_t)NG * KCAP * GW * 4);
  float*    g_t0   = (float*)A((size_t)NG * KCAP * 8);

  const int nbN = (n + 255) / 256;
  const int nbS = (ne + 1024 * EPT - 1) / (1024 * EPT);

  k_zero<<<1, 1024, 0, stream>>>(bincnt, counters, smax_e, sumex);
  k_scatter<<<nbS, 1024, 0, stream>>>(src, dst, ne, shift, cap, bincnt, sorted,
                                      x, gcn_w, xw, n);
  k_c1<<<NBIN, 256, 0, stream>>>(sorted, bincnt, cap, xw, dinv, y, n, shift);
  k_c2<<<NBIN, 256, 0, stream>>>(sorted, bincnt, cap, y, xw, dinv, batch, gcn_b,
                                 topk_w, s_raw, smax_e, sumex, n, shift);
  k_compact_n<<<nbN, 256, 0, stream>>>(s_raw, sumex, smax_e, batch, x, kmap,
                                       kbatch, hk, degfc, counters, n);
  k_compact_e<<<NBIN, 256, 0, stream>>>(sorted, bincnt, cap, kmap, eks, ekd,
                                        degfc, counters, n, shift);
  k_tail<<<NG, 256, 0, stream>>>(hk, kbatch, counters, eks, ekd, degfc,
                                 c0w0, c0w1, c0b, c1w0, c1w1, c1b, c2w0, c2w1, c2b,
                                 bng, bnb, bnm, bnv, l0w, l0b, l1w, l1b, lfw, lfb,
                                 g_hA, g_hB, g_tx, g_t0, out);
}

// Round 8
// 100.650 us; speedup vs baseline: 1.0262x; 1.0023x over previous
//
#include <hip/hip_runtime.h>
#include <math.h>

#define NG 16
#define GW 128
#define NEGV -1.0e9f
#define EPSBN 1e-5f
#define MIN_SCORE 0.1f
#define TOLK 1e-7f
#define NBIN 1024
#define NPBMAX 256
#define EPT 4            // edges per thread in scatter (4 -> 392 blocks: full CU coverage)
#define KCAP 256         // global kept-node cap
#define ECAP 2048        // surviving-edge cap
#define ROWCAP 16        // per-graph LDS fast-path row cap
#define LECAP 256        // per-graph LDS fast-path edge cap
#define TT 1024          // k_tail threads (16 waves: latency hiding in serial phases)

// ---------- helpers ----------
__device__ __forceinline__ unsigned encf(float f) {
  unsigned u = __float_as_uint(f);
  return (u & 0x80000000u) ? ~u : (u | 0x80000000u);
}
__device__ __forceinline__ float decf(unsigned u) {
  unsigned b = (u & 0x80000000u) ? (u & 0x7fffffffu) : ~u;
  return __uint_as_float(b);
}
__device__ __forceinline__ float eluf(float v) { return v > 0.0f ? v : expm1f(v); }

// stage a 128x128 f32 matrix into LDS: batched loads (regs first) then LDS writes
__device__ __forceinline__ void stage_w(const float* __restrict__ w, float* wbuf, int t) {
  const float4* w4 = (const float4*)w;
  float4* b4 = (float4*)wbuf;
  float4 r0 = w4[t], r1 = w4[t + 1024], r2 = w4[t + 2048], r3 = w4[t + 3072];
  b4[t] = r0; b4[t + 1024] = r1; b4[t + 2048] = r2; b4[t + 3072] = r3;
}

// ---------- kernels ----------
__global__ void k_zero(int* __restrict__ bincnt, int* __restrict__ counters,
                       unsigned* __restrict__ smax_e, float* __restrict__ sumex) {
  int t = threadIdx.x;
  for (int i = t; i < NBIN; i += blockDim.x) bincnt[i] = 0;
  if (t < NG) { smax_e[t] = encf(-INFINITY); sumex[t] = 0.0f; }
  if (t == 0) { counters[0] = 0; counters[1] = 0; }
}

// direct bucketed scatter (per-bin capacity regions) + xw init
__global__ __launch_bounds__(1024) void k_scatter(
    const int* __restrict__ src, const int* __restrict__ dst, int ne, int shift,
    int cap, int* __restrict__ bincnt, unsigned* __restrict__ sorted,
    const float* __restrict__ x, const float* __restrict__ gcn_w,
    float* __restrict__ xw, int n) {
  __shared__ int lh[NBIN];
  __shared__ int gb[NBIN];
  int t = threadIdx.x;
  long gid = (long)blockIdx.x * 1024 + t;
  long gs = (long)gridDim.x * 1024;
  float w0 = gcn_w[0], w1 = gcn_w[1];
  for (long i = gid; i < n; i += gs) xw[i] = x[2 * i] * w0 + x[2 * i + 1] * w1;
  for (int b = t; b < NBIN; b += 1024) lh[b] = 0;
  __syncthreads();
  long ebase = (long)blockIdx.x * (1024 * EPT);
  int rank[EPT], dv[EPT];
  #pragma unroll
  for (int k = 0; k < EPT; ++k) {
    long e = ebase + (long)k * 1024 + t;
    rank[k] = 0; dv[k] = 0;
    if (e < ne) { dv[k] = dst[e]; rank[k] = atomicAdd(&lh[dv[k] >> shift], 1); }
  }
  __syncthreads();
  for (int b = t; b < NBIN; b += 1024)
    gb[b] = lh[b] ? atomicAdd(&bincnt[b], lh[b]) : 0;
  __syncthreads();
  #pragma unroll
  for (int k = 0; k < EPT; ++k) {
    long e = ebase + (long)k * 1024 + t;
    if (e < ne) {
      int d = dv[k], bin = d >> shift;
      int pos = gb[bin] + rank[k];
      if (pos < cap)
        sorted[(size_t)bin * cap + pos] =
            ((unsigned)(d & ((1 << shift) - 1)) << 24) | (unsigned)src[e];
    }
  }
}

// per-bucket: deg count (LDS) -> dinv + y = xw*dinv   (uint4-vectorized reads)
__global__ void k_c1(const unsigned* __restrict__ sorted, const int* __restrict__ bincnt,
                     int cap, const float* __restrict__ xw, float* __restrict__ dinv,
                     float* __restrict__ y, int n, int shift) {
  __shared__ int ldeg[NPBMAX];
  int b = blockIdx.x;
  int off = b << shift;
  if (off >= n) return;
  int npb = 1 << shift;
  int t = threadIdx.x;
  for (int j = t; j < npb; j += blockDim.x) ldeg[j] = 0;
  __syncthreads();
  const uint4* s4 = (const uint4*)(sorted + (size_t)b * cap);
  int cnt = bincnt[b]; if (cnt > cap) cnt = cap;
  int nv = cnt >> 2;
  for (int i = t; i < nv; i += blockDim.x) {
    uint4 p = s4[i];
    atomicAdd(&ldeg[p.x >> 24], 1);
    atomicAdd(&ldeg[p.y >> 24], 1);
    atomicAdd(&ldeg[p.z >> 24], 1);
    atomicAdd(&ldeg[p.w >> 24], 1);
  }
  const unsigned* ss = sorted + (size_t)b * cap;
  for (int i = (nv << 2) + t; i < cnt; i += blockDim.x)
    atomicAdd(&ldeg[ss[i] >> 24], 1);
  __syncthreads();
  for (int j = t; j < npb; j += blockDim.x) {
    int g = off + j;
    if (g < n) {
      float dv = rsqrtf((float)(ldeg[j] + 1));   // +1 self loop
      dinv[g] = dv;
      y[g] = xw[g] * dv;
    }
  }
}

// per-bucket: agg -> s_raw; per-graph max AND unnormalized sum(exp(s))
__global__ void k_c2(const unsigned* __restrict__ sorted, const int* __restrict__ bincnt,
                     int cap, const float* __restrict__ y, const float* __restrict__ xw,
                     const float* __restrict__ dinv, const int* __restrict__ batch,
                     const float* __restrict__ gcn_b, const float* __restrict__ topk_w,
                     float* __restrict__ s_raw, unsigned* __restrict__ smax_e,
                     float* __restrict__ sumex, int n, int shift) {
  __shared__ float lt[NPBMAX];
  __shared__ unsigned ls[NG];
  __shared__ float lsum[NG];
  int b = blockIdx.x;
  int off = b << shift;
  if (off >= n) return;
  int npb = 1 << shift;
  int t = threadIdx.x;
  for (int j = t; j < npb; j += blockDim.x) lt[j] = 0.0f;
  if (t < NG) { ls[t] = encf(-INFINITY); lsum[t] = 0.0f; }
  __syncthreads();
  const uint4* s4 = (const uint4*)(sorted + (size_t)b * cap);
  int cnt = bincnt[b]; if (cnt > cap) cnt = cap;
  int nv = cnt >> 2;
  for (int i = t; i < nv; i += blockDim.x) {
    uint4 p = s4[i];
    float ya = y[p.x & 0xFFFFFFu];
    float yb = y[p.y & 0xFFFFFFu];
    float yc = y[p.z & 0xFFFFFFu];
    float yd = y[p.w & 0xFFFFFFu];
    atomicAdd(&lt[p.x >> 24], ya);
    atomicAdd(&lt[p.y >> 24], yb);
    atomicAdd(&lt[p.z >> 24], yc);
    atomicAdd(&lt[p.w >> 24], yd);
  }
  const unsigned* ss = sorted + (size_t)b * cap;
  for (int i = (nv << 2) + t; i < cnt; i += blockDim.x) {
    unsigned p = ss[i];
    atomicAdd(&lt[p >> 24], y[p & 0xFFFFFFu]);
  }
  __syncthreads();
  float gb_ = gcn_b[0], tw = topk_w[0];
  for (int j = t; j < npb; j += blockDim.x) {
    int g = off + j;
    if (g < n) {
      float dv = dinv[g];
      float attn = dv * lt[j] + xw[g] * dv * dv + gb_;
      float s = attn * tw;
      s_raw[g] = s;
      int bb = batch[g];
      atomicMax(&ls[bb], encf(s));
      atomicAdd(&lsum[bb], expf(s));
    }
  }
  __syncthreads();
  if (t < NG) {
    if (ls[t] != encf(-INFINITY)) atomicMax(&smax_e[t], ls[t]);
    if (lsum[t] != 0.0f) atomicAdd(&sumex[t], lsum[t]);
  }
}

__global__ void k_compact_n(const float* __restrict__ s_raw, const float* __restrict__ sumex,
                            const unsigned* __restrict__ smax_e,
                            const int* __restrict__ batch, const float* __restrict__ x,
                            int* __restrict__ kmap, int* __restrict__ kbatch,
                            float* __restrict__ hk, float* __restrict__ degfc,
                            int* __restrict__ counters, int n) {
  int i = blockIdx.x * blockDim.x + threadIdx.x;
  if (i >= n) return;
  if (i < KCAP) degfc[i] = 0.0f;                  // idempotent pre-zero for compact_e
  int b = batch[i];
  float se = sumex[b];
  float score = expf(s_raw[i]) / se;
  float ms = expf(decf(smax_e[b])) / se;          // == max score (monotone fp)
  float thr = fminf(ms - TOLK, MIN_SCORE);
  int m = -1;
  if (score > thr) {
    int idx = atomicAdd(&counters[0], 1);
    if (idx < KCAP) {
      m = idx;
      kbatch[idx] = b;
      hk[2 * idx]     = x[2 * i] * score;
      hk[2 * idx + 1] = x[2 * i + 1] * score;
    }
  }
  kmap[i] = m;
}

// per-bucket surviving-edge compaction (uint4-vectorized)
__global__ void k_compact_e(const unsigned* __restrict__ sorted, const int* __restrict__ bincnt,
                            int cap, const int* __restrict__ kmap,
                            int* __restrict__ eks, int* __restrict__ ekd,
                            float* __restrict__ degfc, int* __restrict__ counters,
                            int n, int shift) {
  int b = blockIdx.x;
  int off = b << shift;
  if (off >= n) return;
  const uint4* s4 = (const uint4*)(sorted + (size_t)b * cap);
  int cnt = bincnt[b]; if (cnt > cap) cnt = cap;
  int nv = cnt >> 2;
  auto proc = [&](unsigned p) {
    int ks = kmap[p & 0xFFFFFFu];
    if (ks < 0) return;
    int kd = kmap[off + (int)(p >> 24)];
    if (kd < 0) return;
    int j = atomicAdd(&counters[1], 1);
    if (j < ECAP) {
      eks[j] = ks;
      ekd[j] = kd;
      atomicAdd(&degfc[kd], 1.0f);
    }
  };
  for (int i = threadIdx.x; i < nv; i += blockDim.x) {
    uint4 p = s4[i];
    proc(p.x); proc(p.y); proc(p.z); proc(p.w);
  }
  const unsigned* ss = sorted + (size_t)b * cap;
  for (int i = (nv << 2) + threadIdx.x; i < cnt; i += blockDim.x) proc(ss[i]);
}

// slow-path cheb layer (global buffers, direct weight loads) — effectively unreachable
__device__ void tail_layer_slow(const float* hin, float* tx, float* hout,
                                const float* __restrict__ w0, const float* __restrict__ w1,
                                const float* __restrict__ cb,
                                const float* __restrict__ bng, const float* __restrict__ bnb,
                                const float* __restrict__ bnm, const float* __restrict__ bnv,
                                int L, int R, int S,
                                const int* kl, const int* rows_g,
                                const int* __restrict__ kbatch,
                                const int* __restrict__ eks, const int* __restrict__ ekd,
                                const float* __restrict__ degfc,
                                unsigned* lgm, int g, int t) {
  for (int i = t; i < R * GW; i += TT) tx[i] = 0.0f;
  __syncthreads();
  for (int e = t; e < S; e += TT) {
    int kd = ekd[e];
    int dr = kl[kd];
    if (dr < 0) continue;
    int sr = kl[eks[e]];
    if (sr < 0) continue;
    float dfs = degfc[eks[e]], dfd = degfc[kd];
    float nf = (dfs > 0.f ? rsqrtf(dfs) : 0.f) * (dfd > 0.f ? rsqrtf(dfd) : 0.f);
    for (int c = 0; c < GW; ++c)
      atomicAdd(&tx[dr * GW + c], -hin[sr * GW + c] * nf);
  }
  __syncthreads();
  int j = t & 127, ih = t >> 7;
  float sc = bng[L * GW + j] * rsqrtf(bnv[L * GW + j] + EPSBN);
  float mn = bnm[L * GW + j], bt = bnb[L * GW + j], bj = cb[j];
  for (int i = ih; i < R; i += 8) {
    float acc = bj;
    for (int k = 0; k < GW; ++k)
      acc += hin[i * GW + k] * w0[k * GW + j] + tx[i * GW + k] * w1[k * GW + j];
    float v = eluf(acc);
    v = (v - mn) * sc + bt;
    if (hout) hout[i * GW + j] = v;
    if (kbatch[rows_g[i]] == g) atomicMax(&lgm[L * GW + j], encf(v));
  }
  __syncthreads();
}

// fast-path cheb layer: weights staged in LDS, static-unrolled row accs (rows stride 8)
template <int MR>
__device__ void layer_fast(const float* hin, const float* txl, float* hout,
                           const float* __restrict__ w0g, const float* __restrict__ w1g,
                           const float* __restrict__ cb,
                           const float* __restrict__ bng, const float* __restrict__ bnb,
                           const float* __restrict__ bnm, const float* __restrict__ bnv,
                           int L, int R, const int* rows_g,
                           const int* __restrict__ kbatch,
                           unsigned* lgm, float* wbuf, int g, int t) {
  int j = t & 127, ih = t >> 7;
  float bj = cb[j];
  float acc[MR];
  #pragma unroll
  for (int r = 0; r < MR; ++r) acc[r] = bj;
  stage_w(w0g, wbuf, t);
  __syncthreads();
  for (int k = 0; k < GW; ++k) {
    float wv = wbuf[k * GW + j];
    #pragma unroll
    for (int r = 0; r < MR; ++r) {
      int row = ih + 8 * r;
      if (row < R) acc[r] += hin[row * GW + k] * wv;
    }
  }
  __syncthreads();
  stage_w(w1g, wbuf, t);
  __syncthreads();
  for (int k = 0; k < GW; ++k) {
    float wv = wbuf[k * GW + j];
    #pragma unroll
    for (int r = 0; r < MR; ++r) {
      int row = ih + 8 * r;
      if (row < R) acc[r] += txl[row * GW + k] * wv;
    }
  }
  float sc = bng[L * GW + j] * rsqrtf(bnv[L * GW + j] + EPSBN);
  float mn = bnm[L * GW + j], bt = bnb[L * GW + j];
  #pragma unroll
  for (int r = 0; r < MR; ++r) {
    int row = ih + 8 * r;
    if (row < R) {
      float v = eluf(acc[r]);
      v = (v - mn) * sc + bt;
      if (hout) hout[row * GW + j] = v;
      if (kbatch[rows_g[row]] == g) atomicMax(&lgm[L * GW + j], encf(v));
    }
  }
  __syncthreads();
}

// 16 blocks, one per graph, 1024 threads: halo rows, 3x(agg+cheb+bn), MLP, log_softmax
__global__ __launch_bounds__(TT) void k_tail(
    const float* __restrict__ hk, const int* __restrict__ kbatch,
    const int* __restrict__ counters,
    const int* __restrict__ eks, const int* __restrict__ ekd,
    const float* __restrict__ degfc,
    const float* __restrict__ c0w0, const float* __restrict__ c0w1, const float* __restrict__ c0b,
    const float* __restrict__ c1w0, const float* __restrict__ c1w1, const float* __restrict__ c1b,
    const float* __restrict__ c2w0, const float* __restrict__ c2w1, const float* __restrict__ c2b,
    const float* __restrict__ bng, const float* __restrict__ bnb,
    const float* __restrict__ bnm, const float* __restrict__ bnv,
    const float* __restrict__ l0w, const float* __restrict__ l0b,
    const float* __restrict__ l1w, const float* __restrict__ l1b,
    const float* __restrict__ lfw, const float* __restrict__ lfb,
    float* __restrict__ g_hA, float* __restrict__ g_hB, float* __restrict__ g_tx,
    float* __restrict__ g_t0, float* __restrict__ out) {
  __shared__ float wbuf[GW * GW];                       // 64 KB weight stage
  __shared__ float sA[ROWCAP * GW], sB[ROWCAP * GW], sT[ROWCAP * GW];
  __shared__ float t0v[ROWCAP * 2];
  __shared__ int kl[KCAP];
  __shared__ int rows_g[KCAP];
  __shared__ int les[LECAP], led[LECAP];
  __shared__ float lenf[LECAP];
  __shared__ unsigned lgm[3 * GW];
  __shared__ int cnts[2];
  __shared__ float red[TT];
  __shared__ float mlp0[32], mlp1[8], lg3[3];

  int g = blockIdx.x, t = threadIdx.x;
  int K = counters[0]; if (K > KCAP) K = KCAP;
  int S = counters[1]; if (S > ECAP) S = ECAP;
  if (t == 0) { cnts[0] = 0; cnts[1] = 0; }
  for (int i = t; i < KCAP; i += TT) kl[i] = -1;
  for (int i = t; i < 3 * GW; i += TT) lgm[i] = encf(NEGV);
  __syncthreads();
  for (int i = t; i < K; i += TT)
    if (kbatch[i] == g) { int r = atomicAdd(&cnts[0], 1); rows_g[r] = i; }
  __syncthreads();
  int R0 = cnts[0];
  for (int r = t; r < R0; r += TT) kl[rows_g[r]] = r;
  __syncthreads();
  // 2-hop halo expansion (serial, S is tiny)
  if (t == 0) {
    for (int pass = 0; pass < 2; ++pass) {
      int Rcur = cnts[0];
      for (int e = 0; e < S; ++e) {
        int kd = ekd[e];
        if (kl[kd] >= 0 && kl[kd] < Rcur) {
          int ks = eks[e];
          if (kl[ks] < 0) { int r = cnts[0]++; rows_g[r] = ks; kl[ks] = r; }
        }
      }
    }
  }
  __syncthreads();
  int R = cnts[0];
  // local edge list (edges into any local row)
  for (int e = t; e < S; e += TT) {
    int kd = ekd[e];
    if (kl[kd] >= 0) {
      int j = atomicAdd(&cnts[1], 1);
      if (j < LECAP) {
        les[j] = eks[e];
        led[j] = kl[kd];
        float dfs = degfc[eks[e]], dfd = degfc[kd];
        lenf[j] = (dfs > 0.f ? rsqrtf(dfs) : 0.f) * (dfd > 0.f ? rsqrtf(dfd) : 0.f);
      }
    }
  }
  __syncthreads();
  int LE = cnts[1]; if (LE > LECAP) LE = LECAP;
  bool fast = (R <= ROWCAP) && (cnts[1] <= LECAP);

  if (fast) {
    // --- layer 0 (D=2), weights tiny: direct ---
    for (int i = t; i < R * 2; i += TT) t0v[i] = 0.0f;
    __syncthreads();
    for (int idx = t; idx < LE * 2; idx += TT) {
      int e = idx >> 1, c = idx & 1;
      atomicAdd(&t0v[led[e] * 2 + c], -hk[les[e] * 2 + c] * lenf[e]);
    }
    __syncthreads();
    {
      int j = t & 127, ih = t >> 7;
      float sc = bng[j] * rsqrtf(bnv[j] + EPSBN);
      float mn = bnm[j], bt = bnb[j];
      for (int i = ih; i < R; i += 8) {
        int gi = rows_g[i];
        float acc = c0b[j] + hk[gi * 2] * c0w0[j] + hk[gi * 2 + 1] * c0w0[GW + j]
                  + t0v[i * 2] * c0w1[j] + t0v[i * 2 + 1] * c0w1[GW + j];
        float v = eluf(acc);
        v = (v - mn) * sc + bt;
        sA[i * GW + j] = v;
        if (kbatch[gi] == g) atomicMax(&lgm[j], encf(v));
      }
    }
    __syncthreads();
    // --- layer 1: agg(sA)->sT, MM staged -> sB ---
    for (int i = t; i < R * GW; i += TT) sT[i] = 0.0f;
    __syncthreads();
    for (int idx = t; idx < LE * GW; idx += TT) {
      int e = idx >> 7, c = idx & 127;
      int sr = kl[les[e]];
      if (sr >= 0) atomicAdd(&sT[led[e] * GW + c], -sA[sr * GW + c] * lenf[e]);
    }
    __syncthreads();
    if (R <= 8)
      layer_fast<1>(sA, sT, sB, c1w0, c1w1, c1b, bng, bnb, bnm, bnv, 1, R,
                    rows_g, kbatch, lgm, wbuf, g, t);
    else
      layer_fast<2>(sA, sT, sB, c1w0, c1w1, c1b, bng, bnb, bnm, bnv, 1, R,
                    rows_g, kbatch, lgm, wbuf, g, t);
    // --- layer 2: agg(sB)->sT, MM staged (no store) ---
    for (int i = t; i < R * GW; i += TT) sT[i] = 0.0f;
    __syncthreads();
    for (int idx = t; idx < LE * GW; idx += TT) {
      int e = idx >> 7, c = idx & 127;
      int sr = kl[les[e]];
      if (sr >= 0) atomicAdd(&sT[led[e] * GW + c], -sB[sr * GW + c] * lenf[e]);
    }
    __syncthreads();
    if (R <= 8)
      layer_fast<1>(sB, sT, nullptr, c2w0, c2w1, c2b, bng, bnb, bnm, bnv, 2, R,
                    rows_g, kbatch, lgm, wbuf, g, t);
    else
      layer_fast<2>(sB, sT, nullptr, c2w0, c2w1, c2b, bng, bnb, bnm, bnv, 2, R,
                    rows_g, kbatch, lgm, wbuf, g, t);
  } else {
    // --- slow path: global buffers (R > ROWCAP; effectively unreachable) ---
    float* hA  = g_hA + (size_t)g * KCAP * GW;
    float* hB  = g_hB + (size_t)g * KCAP * GW;
    float* tx  = g_tx + (size_t)g * KCAP * GW;
    float* t0p = g_t0 + (size_t)g * KCAP * 2;
    for (int i = t; i < R * 2; i += TT) t0p[i] = 0.0f;
    __syncthreads();
    for (int e = t; e < S; e += TT) {
      int kd = ekd[e];
      int dr = kl[kd];
      if (dr < 0) continue;
      int ks = eks[e];
      float dfs = degfc[ks], dfd = degfc[kd];
      float nf = (dfs > 0.f ? rsqrtf(dfs) : 0.f) * (dfd > 0.f ? rsqrtf(dfd) : 0.f);
      atomicAdd(&t0p[dr * 2],     -hk[ks * 2] * nf);
      atomicAdd(&t0p[dr * 2 + 1], -hk[ks * 2 + 1] * nf);
    }
    __syncthreads();
    {
      int j = t & 127, ih = t >> 7;
      float sc = bng[j] * rsqrtf(bnv[j] + EPSBN);
      float mn = bnm[j], bt = bnb[j];
      for (int i = ih; i < R; i += 8) {
        int gi = rows_g[i];
        float acc = c0b[j] + hk[gi * 2] * c0w0[j] + hk[gi * 2 + 1] * c0w0[GW + j]
                  + t0p[i * 2] * c0w1[j] + t0p[i * 2 + 1] * c0w1[GW + j];
        float v = eluf(acc);
        v = (v - mn) * sc + bt;
        hA[i * GW + j] = v;
        if (kbatch[gi] == g) atomicMax(&lgm[j], encf(v));
      }
    }
    __syncthreads();
    tail_layer_slow(hA, tx, hB, c1w0, c1w1, c1b, bng, bnb, bnm, bnv, 1, R, S,
                    kl, rows_g, kbatch, eks, ekd, degfc, lgm, g, t);
    tail_layer_slow(hB, tx, nullptr, c2w0, c2w1, c2b, bng, bnb, bnm, bnv, 2, R, S,
                    kl, rows_g, kbatch, eks, ekd, degfc, lgm, g, t);
  }

  // --- MLP: stage l0w(12288)+l1w(256)+lfw(24) into wbuf (batched) ---
  {
    const float4* a4 = (const float4*)l0w;
    float4* b4 = (float4*)wbuf;
    float4 r0 = a4[t], r1 = a4[t + 1024], r2 = a4[t + 2048];
    b4[t] = r0; b4[t + 1024] = r1; b4[t + 2048] = r2;
    if (t < 256) wbuf[12288 + t] = l1w[t];
    if (t < 24) wbuf[12544 + t] = lfw[t];
  }
  __syncthreads();
  // lin0: 32 outputs x 32 k-chunks of 12
  {
    int jo = t & 31, kb = t >> 5;
    float a = 0.f;
    #pragma unroll
    for (int kk = 0; kk < 12; ++kk) {
      int k = kb * 12 + kk;
      a += decf(lgm[k]) * wbuf[k * 32 + jo];
    }
    red[t] = a;
  }
  __syncthreads();
  if (t < 32) {
    float acc = l0b[t];
    for (int b2 = 0; b2 < 32; ++b2) acc += red[b2 * 32 + t];
    mlp0[t] = eluf(acc);
  }
  __syncthreads();
  if (t < 8) {
    float acc = l1b[t];
    for (int k = 0; k < 32; ++k) acc += mlp0[k] * wbuf[12288 + k * 8 + t];
    mlp1[t] = eluf(acc);
  }
  __syncthreads();
  if (t < 3) {
    float acc = lfb[t];
    for (int k = 0; k < 8; ++k) acc += mlp1[k] * wbuf[12544 + k * 3 + t];
    lg3[t] = acc;
  }
  __syncthreads();
  if (t == 0) {
    float a = lg3[0], b = lg3[1], c = lg3[2];
    float m = fmaxf(a, fmaxf(b, c));
    float ls = m + logf(expf(a - m) + expf(b - m) + expf(c - m));
    out[g * 3 + 0] = a - ls;
    out[g * 3 + 1] = b - ls;
    out[g * 3 + 2] = c - ls;
  }
}

// ---------- launcher ----------
extern "C" void kernel_launch(void* const* d_in, const int* in_sizes, int n_in,
                              void* d_out, int out_size, void* d_ws, size_t ws_size,
                              hipStream_t stream) {
  const float* x      = (const float*)d_in[0];
  const int*   ei     = (const int*)d_in[1];
  const int*   batch  = (const int*)d_in[2];
  const float* gcn_w  = (const float*)d_in[3];
  const float* gcn_b  = (const float*)d_in[4];
  const float* topk_w = (const float*)d_in[5];
  const float* c0w0 = (const float*)d_in[6],  *c0w1 = (const float*)d_in[7],  *c0b = (const float*)d_in[8];
  const float* c1w0 = (const float*)d_in[9],  *c1w1 = (const float*)d_in[10], *c1b = (const float*)d_in[11];
  const float* c2w0 = (const float*)d_in[12], *c2w1 = (const float*)d_in[13], *c2b = (const float*)d_in[14];
  const float* bng = (const float*)d_in[15], *bnb = (const float*)d_in[16];
  const float* bnm = (const float*)d_in[17], *bnv = (const float*)d_in[18];
  const float* l0w = (const float*)d_in[19], *l0b = (const float*)d_in[20];
  const float* l1w = (const float*)d_in[21], *l1b = (const float*)d_in[22];
  const float* lfw = (const float*)d_in[23], *lfb = (const float*)d_in[24];
  float* out = (float*)d_out;

  const int n  = in_sizes[2];       // N nodes
  const int ne = in_sizes[1] / 2;   // E edges
  const int* src = ei;
  const int* dst = ei + ne;

  int shift = 0;
  while (((n - 1) >> shift) >= NBIN) shift++;
  if (shift > 8) shift = 8;  // supports n <= 262144
  const int nbins = ((n - 1) >> shift) + 1;
  int avg = (ne + nbins - 1) / nbins;
  int cap = avg + (int)(8.0 * sqrt((double)avg)) + 64;
  cap = (cap + 15) & ~15;

  char* bp = (char*)d_ws;
  size_t off = 0;
  auto A = [&](size_t bytes) -> void* {
    void* r = (void*)(bp + off);
    off += (bytes + 255) & ~(size_t)255;
    return r;
  };
  float*    xw     = (float*)A((size_t)n * 4);
  float*    dinv   = (float*)A((size_t)n * 4);
  float*    y      = (float*)A((size_t)n * 4);
  float*    s_raw  = (float*)A((size_t)n * 4);
  int*      kmap   = (int*)A((size_t)n * 4);
  unsigned* sorted = (unsigned*)A((size_t)NBIN * cap * 4);
  int*      bincnt = (int*)A(NBIN * 4);
  unsigned* smax_e = (unsigned*)A(NG * 4);
  float*    sumex  = (float*)A(NG * 4);
  int*      counters = (int*)A(8);
  int*      kbatch = (int*)A((size_t)KCAP * 4);
  float*    degfc  = (float*)A((size_t)KCAP * 4);
  float*    hk     = (float*)A((size_t)KCAP * 8);
  int*      eks    = (int*)A((size_t)ECAP * 4);
  int*      ekd    = (int*)A((size_t)ECAP * 4);
  float*    g_hA   = (float*)A((size_t)NG * KCAP * GW * 4);
  float*    g_hB   = (float*)A((size_t)NG * KCAP * GW * 4);
  float*    g_tx   = (float*)A((size_t)NG * KCAP * GW * 4);
  float*    g_t0   = (float*)A((size_t)NG * KCAP * 8);

  const int nbN = (n + 255) / 256;
  const int nbS = (ne + 1024 * EPT - 1) / (1024 * EPT);

  k_zero<<<1, 1024, 0, stream>>>(bincnt, counters, smax_e, sumex);
  k_scatter<<<nbS, 1024, 0, stream>>>(src, dst, ne, shift, cap, bincnt, sorted,
                                      x, gcn_w, xw, n);
  k_c1<<<NBIN, 256, 0, stream>>>(sorted, bincnt, cap, xw, dinv, y, n, shift);
  k_c2<<<NBIN, 256, 0, stream>>>(sorted, bincnt, cap, y, xw, dinv, batch, gcn_b,
                                 topk_w, s_raw, smax_e, sumex, n, shift);
  k_compact_n<<<nbN, 256, 0, stream>>>(s_raw, sumex, smax_e, batch, x, kmap,
                                       kbatch, hk, degfc, counters, n);
  k_compact_e<<<NBIN, 256, 0, stream>>>(sorted, bincnt, cap, kmap, eks, ekd,
                                        degfc, counters, n, shift);
  k_tail<<<NG, TT, 0, stream>>>(hk, kbatch, counters, eks, ekd, degfc,
                                c0w0, c0w1, c0b, c1w0, c1w1, c1b, c2w0, c2w1, c2b,
                                bng, bnb, bnm, bnv, l0w, l0b, l1w, l1b, lfw, lfb,
                                g_hA, g_hB, g_tx, g_t0, out);
}